// Round 8
// baseline (170.747 us; speedup 1.0000x reference)
//
#include <hip/hip_runtime.h>

// ---------------------------------------------------------------------------
// DWT autoencoder round trip. Level-2 dwt2+idwt2 cancel exactly -> LL1r==LL1.
//   K0: rearrange conv weights into consumption order
//   K1: register-blocked fused dwt+conv: each thread owns a 2x2 y-quad
//       (4x weight reuse per 9-weight group), no LDS/barriers, coalesced
//       float4 x loads, rolling band-row pairs per a-tap.
//   K2: convT4x4 s2 of y -> l1 bands, fused with idwt2(LL1, l1) -> out
// B=32, C=3, H=W=512.
// R7 lesson: all 1-px/thread k1 variants stall at ~30% VALUBusy because the
// inner loop needs one fresh weight per FMA (1:1 operand-fetch:FMA). 2x2
// register blocking makes it 1:4 and removes the LDS machinery entirely.
// ---------------------------------------------------------------------------

#define BB 32

// K0: wd[((ch*3+a)*3+q)*27 + band*9 + o] = 0.5 * dw[o, ch*3+band, a, q]
//     wu[((cin*4+rt*2+ct)*4+di*2+dj)*9+o] = uw[cin, o, 3-di-2rt, 3-dj-2ct]
__global__ __launch_bounds__(256) void k0_rearrange(
    const float* __restrict__ dw, const float* __restrict__ uw,
    float* __restrict__ wd, float* __restrict__ wu)
{
    const int t = threadIdx.x;
    for (int i = t; i < 729; i += 256) {
        const int o    = i % 9;
        const int band = (i / 9) % 3;
        const int q    = (i / 27) % 3;
        const int a    = (i / 81) % 3;
        const int ch   = i / 243;
        wd[i] = 0.5f * dw[o * 81 + (ch * 3 + band) * 9 + a * 3 + q];
    }
    for (int i = t; i < 1296; i += 256) {
        const int o = i % 9; int r = i / 9;
        const int dj = r & 1; const int di = (r >> 1) & 1; r >>= 2;
        const int ct = r & 1; const int rt = (r >> 1) & 1; const int cin = r >> 2;
        wu[i] = uw[cin * 144 + o * 16 + (3 - di - 2 * rt) * 4 + (3 - dj - 2 * ct)];
    }
}

// K1: thread owns y rows {2ri,2ri+1} x cols {2cj,2cj+1}. Per (ch,a) it builds
// band rows rA=4ri-1+a (top-px tap) and rB=4ri+1+a (bottom-px tap), 5 band
// cols each, then does 3q x 3band x 9o x 4px FMAs on 81 consecutive weights.
__global__ __launch_bounds__(256, 2) void k1_dwt_down(
    const float* __restrict__ x,     // (B,3,512,512)
    const float* __restrict__ wd,    // reordered (ch,a,q,band,o), x0.5 folded
    const float* __restrict__ db,    // (9)
    float* __restrict__ LL1,         // (B,3,256,256)
    float* __restrict__ y)           // (B,9,128,128)
{
    const int t    = threadIdx.x;
    const int b    = blockIdx.x >> 4;
    const int tile = blockIdx.x & 15;
    const int ri   = ((tile >> 2) << 4) + (t >> 4);   // 0..63 quad-row
    const int cj   = ((tile & 3) << 4) + (t & 15);    // 0..63 quad-col

    float acc[2][2][9];      // [pr][pc][o]
#pragma unroll
    for (int pr = 0; pr < 2; ++pr)
#pragma unroll
        for (int pc = 0; pc < 2; ++pc)
#pragma unroll
            for (int o = 0; o < 9; ++o) acc[pr][pc][o] = db[o];

    const bool cok = (cj > 0);
    const int  xc0 = 8 * cj - 4;     // col of first float4 (valid when cok)

#pragma unroll
    for (int ch = 0; ch < 3; ++ch) {
        const float* xc  = x + ((size_t)b * 3 + ch) * (512 * 512);
        float*       llc = LL1 + ((size_t)b * 3 + ch) * (256 * 256);

#pragma unroll
        for (int a = 0; a < 3; ++a) {
            // band[T][row(0=A,1=B)][k], T: 0=lh 1=hl 2=hh; ll[row][k]
            float bnd[3][2][5];
            float llv[2][5];
#pragma unroll
            for (int rr = 0; rr < 2; ++rr) {
                const int r = 4 * ri - 1 + a + 2 * rr;   // band row
                float4 A0, A1, A2, B0, B1, B2;
                if (r >= 0) {
                    const float* p0 = xc + (size_t)(2 * r) * 512 + xc0;
                    const float* p1 = p0 + 512;
                    A1 = *reinterpret_cast<const float4*>(p0 + 4);
                    A2 = *reinterpret_cast<const float4*>(p0 + 8);
                    B1 = *reinterpret_cast<const float4*>(p1 + 4);
                    B2 = *reinterpret_cast<const float4*>(p1 + 8);
                    if (cok) {
                        A0 = *reinterpret_cast<const float4*>(p0);
                        B0 = *reinterpret_cast<const float4*>(p1);
                    } else {
                        A0 = make_float4(0.f, 0.f, 0.f, 0.f);
                        B0 = make_float4(0.f, 0.f, 0.f, 0.f);
                    }
                } else {
                    A0 = A1 = A2 = make_float4(0.f, 0.f, 0.f, 0.f);
                    B0 = B1 = B2 = make_float4(0.f, 0.f, 0.f, 0.f);
                }
                // x col pairs for band col k: (8cj-2+2k, 8cj-1+2k)
                const float xa[10] = {A0.z, A0.w, A1.x, A1.y, A1.z, A1.w,
                                      A2.x, A2.y, A2.z, A2.w};
                const float xb[10] = {B0.z, B0.w, B1.x, B1.y, B1.z, B1.w,
                                      B2.x, B2.y, B2.z, B2.w};
#pragma unroll
                for (int k = 0; k < 5; ++k) {
                    const float s0 = xa[2 * k] + xa[2 * k + 1];
                    const float d0 = xa[2 * k] - xa[2 * k + 1];
                    const float s1 = xb[2 * k] + xb[2 * k + 1];
                    const float d1 = xb[2 * k] - xb[2 * k + 1];
                    bnd[0][rr][k] = s0 - s1;
                    bnd[1][rr][k] = d0 + d1;
                    bnd[2][rr][k] = d0 - d1;
                    llv[rr][k]    = (s0 + s1) * 0.5f;
                }
            }

            // LL1 stores: rB (=4ri+1+a) always owned; rA owned only at a==1.
            {
                const int rB = 4 * ri + 1 + a;
                float4 v; v.x = llv[1][1]; v.y = llv[1][2];
                v.z = llv[1][3]; v.w = llv[1][4];
                *reinterpret_cast<float4*>(llc + (size_t)rB * 256 + 4 * cj) = v;
                if (a == 1) {
                    float4 u; u.x = llv[0][1]; u.y = llv[0][2];
                    u.z = llv[0][3]; u.w = llv[0][4];
                    *reinterpret_cast<float4*>(llc + (size_t)(4 * ri) * 256 + 4 * cj) = u;
                }
            }

            // FMAs: 81 consecutive weights for this (ch,a); 4x reuse per w9.
            const float* wg = wd + ((ch * 3 + a) * 3) * 27;
#pragma unroll
            for (int q = 0; q < 3; ++q) {
#pragma unroll
                for (int T = 0; T < 3; ++T) {
                    const float* w9 = wg + q * 27 + T * 9;
                    const float vA0 = bnd[T][0][q];
                    const float vA1 = bnd[T][0][q + 2];
                    const float vB0 = bnd[T][1][q];
                    const float vB1 = bnd[T][1][q + 2];
#pragma unroll
                    for (int o = 0; o < 9; ++o) {
                        const float w = w9[o];
                        acc[0][0][o] += vA0 * w;
                        acc[0][1][o] += vA1 * w;
                        acc[1][0][o] += vB0 * w;
                        acc[1][1][o] += vB1 * w;
                    }
                }
            }
        }
    }

    // y stores: float2 per (pr,o)
#pragma unroll
    for (int o = 0; o < 9; ++o)
#pragma unroll
        for (int pr = 0; pr < 2; ++pr) {
            float2 v; v.x = acc[pr][0][o]; v.y = acc[pr][1][o];
            *reinterpret_cast<float2*>(
                y + (((size_t)b * 9 + o) * 128 + 2 * ri + pr) * 128 + 2 * cj) = v;
        }
}

// K2: one block = one batch image, a 32x32 tile at 256-res (=> 64x64 output
// pixels at 512-res), all 3 colors. Each thread owns a 2x2 parity quad; all
// 36 accumulators live (needs VGPR room -> launch_bounds(256,4)).
__global__ __launch_bounds__(256, 4) void k2_up_idwt(
    const float* __restrict__ yg,    // (B,9,128,128)
    const float* __restrict__ wu,    // reordered (cin,rt,ct,di,dj,o)
    const float* __restrict__ ub,    // (9)
    const float* __restrict__ LL1,   // (B,3,256,256)
    float* __restrict__ out)         // (B,3,512,512)
{
    __shared__ float ysh[9][18][19];

    const int t    = threadIdx.x;
    const int b    = blockIdx.x >> 6;
    const int tile = blockIdx.x & 63;
    const int r0   = (tile >> 3) << 5;  // 256-res tile origin
    const int c0   = (tile & 7) << 5;
    const int p0   = (r0 >> 1) - 1;     // y row of local 0
    const int q0   = (c0 >> 1) - 1;

    // ---- stage y tile (18x18 halo, 9 ch) into LDS ----
    for (int item = t; item < 9 * 324; item += 256) {
        const int cin = item / 324;
        int rem       = item - cin * 324;
        const int lp  = rem / 18;
        const int lq  = rem - lp * 18;
        const int p   = p0 + lp, q = q0 + lq;
        float v = 0.f;
        if (p >= 0 && p < 128 && q >= 0 && q < 128)
            v = yg[(((size_t)b * 9 + cin) * 128 + p) * 128 + q];
        ysh[cin][lp][lq] = v;
    }
    __syncthreads();

    const int i2 = t >> 4;   // 0..15
    const int j2 = t & 15;   // 0..15

    float acc[2][2][9];      // [di][dj][out-ch]
#pragma unroll
    for (int di = 0; di < 2; ++di)
#pragma unroll
        for (int dj = 0; dj < 2; ++dj)
#pragma unroll
            for (int o = 0; o < 9; ++o) acc[di][dj][o] = ub[o];

    for (int cin = 0; cin < 9; ++cin) {
        float yv[3][3];
#pragma unroll
        for (int r = 0; r < 3; ++r)
#pragma unroll
            for (int c = 0; c < 3; ++c)
                yv[r][c] = ysh[cin][i2 + r][j2 + c];
        const float* wc = wu + cin * 144;
#pragma unroll
        for (int rt = 0; rt < 2; ++rt)
#pragma unroll
            for (int ct = 0; ct < 2; ++ct) {
                const float* wg = wc + (rt * 2 + ct) * 36;  // 36 consecutive
#pragma unroll
                for (int di = 0; di < 2; ++di)
#pragma unroll
                    for (int dj = 0; dj < 2; ++dj) {
                        const float vv = yv[di + rt][dj + ct];
                        const float* w9 = wg + (di * 2 + dj) * 9;
#pragma unroll
                        for (int o = 0; o < 9; ++o)
                            acc[di][dj][o] += vv * w9[o];
                    }
            }
    }

    // ---- epilogue: idwt2(LL1, LH, HL, HH) -> 4x4 output pixels / color ----
#pragma unroll
    for (int cc = 0; cc < 3; ++cc) {
#pragma unroll
        for (int di = 0; di < 2; ++di) {
            const int I = r0 + 2 * i2 + di;
            const int J = c0 + 2 * j2;
            const float2 llv = *reinterpret_cast<const float2*>(
                LL1 + (((size_t)b * 3 + cc) * 256 + I) * 256 + J);
            float4 top, bot;
            {
                const float ll = llv.x;
                const float lh = acc[di][0][cc * 3 + 0];
                const float hl = acc[di][0][cc * 3 + 1];
                const float hh = acc[di][0][cc * 3 + 2];
                const float e0 = ll + lh, od0 = ll - lh;
                const float e1 = hl + hh, od1 = hl - hh;
                top.x = (e0 + e1) * 0.5f; top.y = (e0 - e1) * 0.5f;
                bot.x = (od0 + od1) * 0.5f; bot.y = (od0 - od1) * 0.5f;
            }
            {
                const float ll = llv.y;
                const float lh = acc[di][1][cc * 3 + 0];
                const float hl = acc[di][1][cc * 3 + 1];
                const float hh = acc[di][1][cc * 3 + 2];
                const float e0 = ll + lh, od0 = ll - lh;
                const float e1 = hl + hh, od1 = hl - hh;
                top.z = (e0 + e1) * 0.5f; top.w = (e0 - e1) * 0.5f;
                bot.z = (od0 + od1) * 0.5f; bot.w = (od0 - od1) * 0.5f;
            }
            float* op = out + (((size_t)b * 3 + cc) * 512 + 2 * I) * 512 + 2 * J;
            *reinterpret_cast<float4*>(op) = top;
            *reinterpret_cast<float4*>(op + 512) = bot;
        }
    }
}

extern "C" void kernel_launch(void* const* d_in, const int* in_sizes, int n_in,
                              void* d_out, int out_size, void* d_ws, size_t ws_size,
                              hipStream_t stream) {
    const float* x  = (const float*)d_in[0];
    const float* dw = (const float*)d_in[1];
    const float* db = (const float*)d_in[2];
    const float* uw = (const float*)d_in[3];
    const float* ub = (const float*)d_in[4];
    float* outp = (float*)d_out;

    float* wsf = (float*)d_ws;
    float* wd  = wsf;            // 729 floats (pad to 768)
    float* wu  = wsf + 768;      // 1296 floats
    float* LL1 = wsf + 2304;                         // 25.2 MB
    float* y   = LL1 + (size_t)BB * 3 * 256 * 256;   // 18.9 MB

    k0_rearrange<<<dim3(1), dim3(256), 0, stream>>>(dw, uw, wd, wu);
    k1_dwt_down<<<dim3(BB * 16), dim3(256), 0, stream>>>(x, wd, db, LL1, y);
    k2_up_idwt<<<dim3(BB * 64), dim3(256), 0, stream>>>(y, wu, ub, LL1, outp);
}

// Round 9
// 82.645 us; speedup vs baseline: 2.0660x; 2.0660x over previous
//
#include <hip/hip_runtime.h>

// ---------------------------------------------------------------------------
// DWT autoencoder round trip. Level-2 dwt2+idwt2 cancel exactly -> LL1r==LL1.
//   K0: rearrange conv weights into consumption order + zero-page
//   K1: ONE-SHOT gload_lds staging of all 3 channels (61.4KB LDS, max MLP,
//       single barrier), then verified dwt+conv compute. XCD block swizzle.
//   K2: convT4x4 s2 of y -> l1 bands, fused with idwt2(LL1, l1) -> out
// B=32, C=3, H=W=512.
// R8 lesson: 2x2 reg-blocking spilled (VGPR cap 128, +230MB scratch traffic).
// R3-R7 lessons: per-channel staging phases expose latency; one-shot staging
// with deep MLP was the best structure. This round = one-shot + gload_lds.
// ---------------------------------------------------------------------------

#define BB 32

// K0: wd[((ch*3+a)*3+q)*27 + band*9 + o] = 0.5 * dw[o, ch*3+band, a, q]
//     wu[((cin*4+rt*2+ct)*4+di*2+dj)*9+o] = uw[cin, o, 3-di-2rt, 3-dj-2ct]
//     zp[0..15] = 0 (zero-page for invalid gload lanes)
__global__ __launch_bounds__(256) void k0_rearrange(
    const float* __restrict__ dw, const float* __restrict__ uw,
    float* __restrict__ wd, float* __restrict__ wu, float* __restrict__ zp)
{
    const int t = threadIdx.x;
    for (int i = t; i < 729; i += 256) {
        const int o    = i % 9;
        const int band = (i / 9) % 3;
        const int q    = (i / 27) % 3;
        const int a    = (i / 81) % 3;
        const int ch   = i / 243;
        wd[i] = 0.5f * dw[o * 81 + (ch * 3 + band) * 9 + a * 3 + q];
    }
    for (int i = t; i < 1296; i += 256) {
        const int o = i % 9; int r = i / 9;
        const int dj = r & 1; const int di = (r >> 1) & 1; r >>= 2;
        const int ct = r & 1; const int rt = (r >> 1) & 1; const int cin = r >> 2;
        wu[i] = uw[cin * 144 + o * 16 + (3 - di - 2 * rt) * 4 + (3 - dj - 2 * ct)];
    }
    if (t < 16) zp[t] = 0.f;
}

__device__ __forceinline__ void gload16(const float* gp, float* lp) {
    __builtin_amdgcn_global_load_lds(
        (const __attribute__((address_space(1))) void*)gp,
        (__attribute__((address_space(3))) void*)lp, 16, 0, 0);
}

// K1: block = 16x16 y-tile. Per channel the x tile is 66 rows x 17 float4 =
// 1122 slots, padded to 1280 (=5*256) so every gload instruction is issued
// by a full wave (no mid-wave cutoff -> no same-address completion races;
// invalid lanes read the zero-page, junk lands in pad slots never read).
// All 15 gloads/thread issued back-to-back -> ~15KB/wave in flight, then ONE
// barrier, then the verified band+conv compute.
__global__ __launch_bounds__(256) void k1_dwt_down(
    const float* __restrict__ x,     // (B,3,512,512)
    const float* __restrict__ wd,    // reordered (ch,a,q,band,o), x0.5 folded
    const float* __restrict__ db,    // (9)
    const float* __restrict__ zp,    // 16-float zero page
    float* __restrict__ LL1,         // (B,3,256,256)
    float* __restrict__ y)           // (B,9,128,128)
{
    __shared__ float xs[3 * 5120];   // 3 channels x 1280 f4 slots = 61.44 KB

    const int t    = threadIdx.x;
    const int bid  = blockIdx.x;
    const int swz  = (bid & 7) * 256 + (bid >> 3);   // XCD-contiguous chunks
    const int b    = swz >> 6;
    const int tile = swz & 63;
    const int i0   = (tile >> 3) << 4;   // y tile origin
    const int j0   = (tile & 7) << 4;
    const int ti   = t >> 4;             // 0..15
    const int tj   = t & 15;             // 0..15
    const int I    = i0 + ti;
    const int J    = j0 + tj;
    const int gr0  = 4 * i0 - 2;         // global x row of LDS row 0
    const int gc0  = 4 * j0 - 4;         // global x col of LDS col 0 (16B aligned)

    // ---- one-shot stage: 3 channels x 5 wave-wide gload rounds ----
#pragma unroll
    for (int ch = 0; ch < 3; ++ch) {
        const float* xc = x + ((size_t)b * 3 + ch) * (512 * 512);
#pragma unroll
        for (int n = 0; n < 5; ++n) {
            const int idx = n * 256 + t;      // slot within channel, 0..1279
            const int lr  = idx / 17;
            const int f4c = idx - lr * 17;
            const int gr  = gr0 + lr;
            const bool ok = (idx < 1122) && (gr >= 0) && !(f4c == 0 && j0 == 0);
            const float* gp = ok ? (xc + (size_t)gr * 512 + gc0 + 4 * f4c) : zp;
            gload16(gp, &xs[(ch * 1280 + idx) * 4]);
        }
    }

    float acc[9];
#pragma unroll
    for (int o = 0; o < 9; ++o) acc[o] = db[o];

    __syncthreads();                          // single drain: all 61KB ready

#pragma unroll
    for (int ch = 0; ch < 3; ++ch) {
        const float* xb  = xs + ch * 5120;
        const float* wch = wd + ch * 243;
        float* llc = LL1 + ((size_t)b * 3 + ch) * (256 * 256);

#pragma unroll
        for (int a = 0; a < 3; ++a) {
            float2 p[2][3];                   // [x-row parity][band-col tap]
#pragma unroll
            for (int rr = 0; rr < 2; ++rr)
#pragma unroll
                for (int k = 0; k < 3; ++k)
                    p[rr][k] = *reinterpret_cast<const float2*>(
                        &xb[(4 * ti + 2 * a + rr) * 68 + 4 * tj + 2 + 2 * k]);

            float lh[3], hl[3], hh[3], llv1, llv2;
            {
                const float s0 = p[0][0].x + p[0][0].y, d0 = p[0][0].x - p[0][0].y;
                const float s1 = p[1][0].x + p[1][0].y, d1 = p[1][0].x - p[1][0].y;
                lh[0] = s0 - s1; hl[0] = d0 + d1; hh[0] = d0 - d1;
            }
            {
                const float s0 = p[0][1].x + p[0][1].y, d0 = p[0][1].x - p[0][1].y;
                const float s1 = p[1][1].x + p[1][1].y, d1 = p[1][1].x - p[1][1].y;
                lh[1] = s0 - s1; hl[1] = d0 + d1; hh[1] = d0 - d1;
                llv1 = (s0 + s1) * 0.5f;
            }
            {
                const float s0 = p[0][2].x + p[0][2].y, d0 = p[0][2].x - p[0][2].y;
                const float s1 = p[1][2].x + p[1][2].y, d1 = p[1][2].x - p[1][2].y;
                lh[2] = s0 - s1; hl[2] = d0 + d1; hh[2] = d0 - d1;
                llv2 = (s0 + s1) * 0.5f;
            }

            // LL1: level-1 row r=2I-1+a (a>=1), cols {2J, 2J+1}
            if (a >= 1) {
                float2 w2; w2.x = llv1; w2.y = llv2;
                *reinterpret_cast<float2*>(llc + (size_t)(2 * I - 1 + a) * 256 + 2 * J) = w2;
            }

            const float* wg = wch + a * 81;
#pragma unroll
            for (int q = 0; q < 3; ++q) {
                const float* w0 = wg + q * 27;   // 27 consecutive uniform weights
#pragma unroll
                for (int o = 0; o < 9; ++o) acc[o] += lh[q] * w0[o];
#pragma unroll
                for (int o = 0; o < 9; ++o) acc[o] += hl[q] * w0[9 + o];
#pragma unroll
                for (int o = 0; o < 9; ++o) acc[o] += hh[q] * w0[18 + o];
            }
        }
    }

#pragma unroll
    for (int o = 0; o < 9; ++o)
        y[(((size_t)b * 9 + o) * 128 + I) * 128 + J] = acc[o];
}

// K2: one block = one batch image, a 32x32 tile at 256-res (=> 64x64 output
// pixels at 512-res), all 3 colors. Each thread owns a 2x2 parity quad; all
// 36 accumulators live (needs VGPR room -> launch_bounds(256,4)).
__global__ __launch_bounds__(256, 4) void k2_up_idwt(
    const float* __restrict__ yg,    // (B,9,128,128)
    const float* __restrict__ wu,    // reordered (cin,rt,ct,di,dj,o)
    const float* __restrict__ ub,    // (9)
    const float* __restrict__ LL1,   // (B,3,256,256)
    float* __restrict__ out)         // (B,3,512,512)
{
    __shared__ float ysh[9][18][19];

    const int t    = threadIdx.x;
    const int b    = blockIdx.x >> 6;
    const int tile = blockIdx.x & 63;
    const int r0   = (tile >> 3) << 5;  // 256-res tile origin
    const int c0   = (tile & 7) << 5;
    const int p0   = (r0 >> 1) - 1;     // y row of local 0
    const int q0   = (c0 >> 1) - 1;

    // ---- stage y tile (18x18 halo, 9 ch) into LDS ----
    for (int item = t; item < 9 * 324; item += 256) {
        const int cin = item / 324;
        int rem       = item - cin * 324;
        const int lp  = rem / 18;
        const int lq  = rem - lp * 18;
        const int p   = p0 + lp, q = q0 + lq;
        float v = 0.f;
        if (p >= 0 && p < 128 && q >= 0 && q < 128)
            v = yg[(((size_t)b * 9 + cin) * 128 + p) * 128 + q];
        ysh[cin][lp][lq] = v;
    }
    __syncthreads();

    const int i2 = t >> 4;   // 0..15
    const int j2 = t & 15;   // 0..15

    float acc[2][2][9];      // [di][dj][out-ch]
#pragma unroll
    for (int di = 0; di < 2; ++di)
#pragma unroll
        for (int dj = 0; dj < 2; ++dj)
#pragma unroll
            for (int o = 0; o < 9; ++o) acc[di][dj][o] = ub[o];

    for (int cin = 0; cin < 9; ++cin) {
        float yv[3][3];
#pragma unroll
        for (int r = 0; r < 3; ++r)
#pragma unroll
            for (int c = 0; c < 3; ++c)
                yv[r][c] = ysh[cin][i2 + r][j2 + c];
        const float* wc = wu + cin * 144;
#pragma unroll
        for (int rt = 0; rt < 2; ++rt)
#pragma unroll
            for (int ct = 0; ct < 2; ++ct) {
                const float* wg = wc + (rt * 2 + ct) * 36;  // 36 consecutive
#pragma unroll
                for (int di = 0; di < 2; ++di)
#pragma unroll
                    for (int dj = 0; dj < 2; ++dj) {
                        const float vv = yv[di + rt][dj + ct];
                        const float* w9 = wg + (di * 2 + dj) * 9;
#pragma unroll
                        for (int o = 0; o < 9; ++o)
                            acc[di][dj][o] += vv * w9[o];
                    }
            }
    }

    // ---- epilogue: idwt2(LL1, LH, HL, HH) -> 4x4 output pixels / color ----
#pragma unroll
    for (int cc = 0; cc < 3; ++cc) {
#pragma unroll
        for (int di = 0; di < 2; ++di) {
            const int I = r0 + 2 * i2 + di;
            const int J = c0 + 2 * j2;
            const float2 llv = *reinterpret_cast<const float2*>(
                LL1 + (((size_t)b * 3 + cc) * 256 + I) * 256 + J);
            float4 top, bot;
            {
                const float ll = llv.x;
                const float lh = acc[di][0][cc * 3 + 0];
                const float hl = acc[di][0][cc * 3 + 1];
                const float hh = acc[di][0][cc * 3 + 2];
                const float e0 = ll + lh, od0 = ll - lh;
                const float e1 = hl + hh, od1 = hl - hh;
                top.x = (e0 + e1) * 0.5f; top.y = (e0 - e1) * 0.5f;
                bot.x = (od0 + od1) * 0.5f; bot.y = (od0 - od1) * 0.5f;
            }
            {
                const float ll = llv.y;
                const float lh = acc[di][1][cc * 3 + 0];
                const float hl = acc[di][1][cc * 3 + 1];
                const float hh = acc[di][1][cc * 3 + 2];
                const float e0 = ll + lh, od0 = ll - lh;
                const float e1 = hl + hh, od1 = hl - hh;
                top.z = (e0 + e1) * 0.5f; top.w = (e0 - e1) * 0.5f;
                bot.z = (od0 + od1) * 0.5f; bot.w = (od0 - od1) * 0.5f;
            }
            float* op = out + (((size_t)b * 3 + cc) * 512 + 2 * I) * 512 + 2 * J;
            *reinterpret_cast<float4*>(op) = top;
            *reinterpret_cast<float4*>(op + 512) = bot;
        }
    }
}

extern "C" void kernel_launch(void* const* d_in, const int* in_sizes, int n_in,
                              void* d_out, int out_size, void* d_ws, size_t ws_size,
                              hipStream_t stream) {
    const float* x  = (const float*)d_in[0];
    const float* dw = (const float*)d_in[1];
    const float* db = (const float*)d_in[2];
    const float* uw = (const float*)d_in[3];
    const float* ub = (const float*)d_in[4];
    float* outp = (float*)d_out;

    float* wsf = (float*)d_ws;
    float* wd  = wsf;            // 729 floats (pad to 768)
    float* wu  = wsf + 768;      // 1296 floats
    float* zp  = wsf + 2240;     // 16-float zero page (16B aligned)
    float* LL1 = wsf + 2304;                         // 25.2 MB
    float* y   = LL1 + (size_t)BB * 3 * 256 * 256;   // 18.9 MB

    k0_rearrange<<<dim3(1), dim3(256), 0, stream>>>(dw, uw, wd, wu, zp);
    k1_dwt_down<<<dim3(BB * 64), dim3(256), 0, stream>>>(x, wd, db, zp, LL1, y);
    k2_up_idwt<<<dim3(BB * 64), dim3(256), 0, stream>>>(y, wu, ub, LL1, outp);
}